// Round 6
// baseline (472.724 us; speedup 1.0000x reference)
//
#include <hip/hip_runtime.h>
#include <stdint.h>
#include <stddef.h>

// ---------- types / helpers ----------
typedef __attribute__((ext_vector_type(8))) short bf16x8;   // 8 bf16 in 4 VGPRs
typedef __attribute__((ext_vector_type(4))) float f32x4;

typedef __attribute__((address_space(1))) unsigned int uint_g;
typedef __attribute__((address_space(3))) unsigned int uint_l;

#define DEV static __device__ __forceinline__

DEV unsigned short f2bf(float f) {          // RNE float -> bf16 bits
  unsigned int u = __float_as_uint(f);
  u += 0x7FFFu + ((u >> 16) & 1u);
  return (unsigned short)(u >> 16);
}

DEV void gl_lds16(const unsigned short* g, unsigned short* l) {
  // async global->LDS, 16B per lane; LDS dest = wave-uniform base + lane*16
  __builtin_amdgcn_global_load_lds((const uint_g*)g, (uint_l*)l, 16, 0, 0);
}

// ---------- elementwise f32 -> bf16 (vectorized x4) ----------
__global__ __launch_bounds__(256) void k_f32_to_bf16(const float* __restrict__ in,
                                                     unsigned short* __restrict__ out, int n4) {
  int i = blockIdx.x * 256 + threadIdx.x;
  if (i >= n4) return;
  const float4 v = ((const float4*)in)[i];
  ushort4 o;
  o.x = f2bf(v.x); o.y = f2bf(v.y); o.z = f2bf(v.z); o.w = f2bf(v.w);
  ((ushort4*)out)[i] = o;
}

// ---------- transpose fp32 [R][C] -> bf16 [C][R] ----------
__global__ __launch_bounds__(256) void k_transpose_to_bf16(const float* __restrict__ in,
                                                           unsigned short* __restrict__ out,
                                                           int R, int C) {
  __shared__ unsigned short tile[32][33];   // +1 pad breaks bank conflicts
  const int c0 = blockIdx.x << 5, r0 = blockIdx.y << 5;
  const int tx = threadIdx.x & 31, ty = threadIdx.x >> 5;   // 32x8
  #pragma unroll
  for (int i = 0; i < 32; i += 8)
    tile[ty + i][tx] = f2bf(in[(size_t)(r0 + ty + i) * C + c0 + tx]);
  __syncthreads();
  #pragma unroll
  for (int i = 0; i < 32; i += 8)
    out[(size_t)(c0 + ty + i) * R + r0 + tx] = tile[tx][ty + i];
}

enum { EPI_BIAS = 0, EPI_VT = 3, EPI_DUAL = 4, EPI_RELU = 5, EPI_RES = 6, EPI_KV = 7 };

// ---------- 256x256 bf16 GEMM, ONE barrier per K-tile ----------
// v6: r5's pipe arithmetic showed the 8-barrier/tile lockstep serializes
// LDS-read (2304 cy/tile/CU) and MFMA (2483 cy/tile/CU) -> 6540 cy/tile
// measured. Within a tile ALL fragment reads hit the resident buffer pb and
// ALL staging goes to the idle buffer qb -> no intra-tile hazard exists.
// Hazards: (H1) tile kt resident before reads  -> vmcnt(0)+barrier at tile
// start (loads were issued a full tile ago, drain is cheap); (H2) staging qb
// only after all waves done reading qb's old tile -> same barrier (each wave
// drained its kt-1 reads before arriving). So: 1 barrier + 1 vmcnt per tile,
// zero intra-tile sync. Waves skew across quadrants -> wave A's MFMA overlaps
// wave B's ds_reads (pipe-level TLP); setprio biases the MFMA wave (T5).
// No explicit lgkmcnt: compiler inserts fine-grained waits from data deps.
// T2 swizzle: LDS[row][c16] = G[row][c16 ^ (row&7)], gl_lds dest linear
// (rule #21), read applies the same XOR. Bank conflicts measured 0.
template <int EPI>
__global__ __launch_bounds__(512, 2)
void k_gemm8(const unsigned short* __restrict__ A, const unsigned short* __restrict__ B,
             int lda, int ldb, int kTiles,
             void* C0, void* C1, const float* bias, const float* bias2, int ldc, float scale) {
  __shared__ unsigned short As[2][256 * 64];   // 32 KB x2
  __shared__ unsigned short Bs[2][256 * 64];   // 32 KB x2

  const int t = threadIdx.x;
  const int lane = t & 63, w = t >> 6;
  const int wm = w >> 2, wn = w & 3;           // 2M x 4N wave grid
  const int frow = lane & 15, quad = lane >> 4;

  const unsigned short* Ab = A + (size_t)blockIdx.y * 256 * lda;
  const unsigned short* Bb = B + (size_t)blockIdx.x * 256 * ldb;

  f32x4 acc[8][4] = {};

  // stage one 128-row half (2 x gl_lds per thread, LDS dest linear lane*16)
  auto stA = [&](int kt, int bi, int h) {
    #pragma unroll
    for (int it = 0; it < 2; ++it) {
      int e = (it << 9) + t;
      int row = (h << 7) + (e >> 3);
      int c16 = (e & 7) ^ (row & 7);
      gl_lds16(Ab + (size_t)row * lda + (kt << 6) + (c16 << 3),
               &As[bi][(row << 6) + ((e & 7) << 3)]);
    }
  };
  auto stB = [&](int kt, int bi, int h) {
    #pragma unroll
    for (int it = 0; it < 2; ++it) {
      int e = (it << 9) + t;
      int row = (h << 7) + (e >> 3);
      int c16 = (e & 7) ^ (row & 7);
      gl_lds16(Bb + (size_t)row * ldb + (kt << 6) + (c16 << 3),
               &Bs[bi][(row << 6) + ((e & 7) << 3)]);
    }
  };
  // swizzled fragment read: row 0..255 (incl frow), ksl in {0,1}
  auto frag = [&](const unsigned short* buf, int row, int ksl) -> bf16x8 {
    int col = ((ksl << 5) + (quad << 3)) ^ ((row & 7) << 3);
    return *(const bf16x8*)&buf[(row << 6) + col];
  };

  // prologue: stage tile 0 (8 loads/wave); drained at the first tile barrier
  stB(0, 0, 0); stB(0, 0, 1); stA(0, 0, 0); stA(0, 0, 1);

  bf16x8 a[4][2], b0[2][2], b1[2][2];
  const int arow = wm << 7, brow = wn << 6;

  for (int kt = 0; kt < kTiles; ++kt) {
    const int pb = kt & 1, qb = pb ^ 1;
    const unsigned short* Ac = As[pb];
    const unsigned short* Bc = Bs[pb];

    // ---- tile start: certify kt (H1) + release qb for staging (H2) ----
    asm volatile("s_waitcnt vmcnt(0)" ::: "memory");   // kt's loads (issued 1 tile ago)
    asm volatile("s_barrier" ::: "memory");

    // stage ALL of kt+1 into qb (idle this whole tile) -> full-tile cover
    if (kt + 1 < kTiles) {
      stB(kt + 1, qb, 0); stB(kt + 1, qb, 1);
      stA(kt + 1, qb, 0); stA(kt + 1, qb, 1);
    }

    // ---- quadrant 0: (mh0, nh0) ----
    #pragma unroll
    for (int m = 0; m < 4; ++m)
      #pragma unroll
      for (int k = 0; k < 2; ++k) a[m][k] = frag(Ac, arow + (m << 4) + frow, k);
    #pragma unroll
    for (int n = 0; n < 2; ++n)
      #pragma unroll
      for (int k = 0; k < 2; ++k) b0[n][k] = frag(Bc, brow + (n << 4) + frow, k);
    __builtin_amdgcn_s_setprio(1);
    #pragma unroll
    for (int m = 0; m < 4; ++m)
      #pragma unroll
      for (int n = 0; n < 2; ++n)
        #pragma unroll
        for (int k = 0; k < 2; ++k)
          acc[m][n] = __builtin_amdgcn_mfma_f32_16x16x32_bf16(a[m][k], b0[n][k], acc[m][n], 0, 0, 0);
    __builtin_amdgcn_s_setprio(0);

    // ---- quadrant 1: (mh0, nh1) ----
    #pragma unroll
    for (int n = 0; n < 2; ++n)
      #pragma unroll
      for (int k = 0; k < 2; ++k) b1[n][k] = frag(Bc, brow + 32 + (n << 4) + frow, k);
    __builtin_amdgcn_s_setprio(1);
    #pragma unroll
    for (int m = 0; m < 4; ++m)
      #pragma unroll
      for (int n = 0; n < 2; ++n)
        #pragma unroll
        for (int k = 0; k < 2; ++k)
          acc[m][2 + n] = __builtin_amdgcn_mfma_f32_16x16x32_bf16(a[m][k], b1[n][k], acc[m][2 + n], 0, 0, 0);
    __builtin_amdgcn_s_setprio(0);

    // ---- quadrant 2: (mh1, nh0) ----
    #pragma unroll
    for (int m = 0; m < 4; ++m)
      #pragma unroll
      for (int k = 0; k < 2; ++k) a[m][k] = frag(Ac, arow + 64 + (m << 4) + frow, k);
    __builtin_amdgcn_s_setprio(1);
    #pragma unroll
    for (int m = 0; m < 4; ++m)
      #pragma unroll
      for (int n = 0; n < 2; ++n)
        #pragma unroll
        for (int k = 0; k < 2; ++k)
          acc[4 + m][n] = __builtin_amdgcn_mfma_f32_16x16x32_bf16(a[m][k], b0[n][k], acc[4 + m][n], 0, 0, 0);
    __builtin_amdgcn_s_setprio(0);

    // ---- quadrant 3: (mh1, nh1) ----
    __builtin_amdgcn_s_setprio(1);
    #pragma unroll
    for (int m = 0; m < 4; ++m)
      #pragma unroll
      for (int n = 0; n < 2; ++n)
        #pragma unroll
        for (int k = 0; k < 2; ++k)
          acc[4 + m][2 + n] = __builtin_amdgcn_mfma_f32_16x16x32_bf16(a[m][k], b1[n][k], acc[4 + m][2 + n], 0, 0, 0);
    __builtin_amdgcn_s_setprio(0);
  }

  // ---- epilogue: C/D layout col=lane&15, row=(lane>>4)*4+reg ----
  const int mb = blockIdx.y * 256 + wm * 128 + (quad << 2);
  const int nb = blockIdx.x * 256 + wn * 64 + frow;
  #pragma unroll
  for (int mi = 0; mi < 8; ++mi) {
    const int m = mb + mi * 16;
    #pragma unroll
    for (int ni = 0; ni < 4; ++ni) {
      const int n = nb + ni * 16;
      f32x4 v = acc[mi][ni];
      if constexpr (EPI == EPI_BIAS) {
        unsigned short* O = (unsigned short*)C0;
        const float bv2 = bias[n];
        #pragma unroll
        for (int r = 0; r < 4; ++r) O[(size_t)(m + r) * ldc + n] = f2bf((v[r] + bv2) * scale);
      } else if constexpr (EPI == EPI_KV) {
        if (n < 2048) {                                  // K path (uniform per block)
          unsigned short* O = (unsigned short*)C0;
          const float bv2 = bias[n];
          #pragma unroll
          for (int r = 0; r < 4; ++r) O[(size_t)(m + r) * ldc + n] = f2bf(v[r] + bv2);
        } else {                                         // V path -> Vt[b][h][d][li]
          const int n2 = n - 2048;
          const int b = m / 576, li = m - b * 576;
          const int h = n2 >> 8, d = n2 & 255;
          const float bv2 = bias2[n2];
          ushort4 o;
          o.x = f2bf(v[0] + bv2); o.y = f2bf(v[1] + bv2);
          o.z = f2bf(v[2] + bv2); o.w = f2bf(v[3] + bv2);
          *(ushort4*)((unsigned short*)C1 + ((size_t)((b * 8 + h) * 256 + d)) * 576 + li) = o;
        }
      }
    }
  }
}

// ---------- generic bf16 MFMA GEMM: C = A @ B^T (+epilogue) ----------
// round-0 form (best 2-phase measured): single-barrier double-buffered K-loop.
// Used for out-proj / ff1 / ff2 (shapes that don't fit 256x256 tiling).
template <int BM, int BN, int EPI>
__global__ __launch_bounds__(256)
void k_gemm(const unsigned short* __restrict__ A, const unsigned short* __restrict__ B,
            int lda, int ldb, int kSteps,
            void* C0, void* C1, const float* bias, const float* resid, int ldc, float scale) {
  constexpr int TM = BM / 32;
  constexpr int TN = BN / 32;
  __shared__ unsigned short At[2][BM * 32];
  __shared__ unsigned short Bt[2][BN * 32];

  const int t = threadIdx.x;
  const int lane = t & 63, wave = t >> 6;
  const int wm = wave >> 1, wn = wave & 1;            // 2x2 wave grid

  const unsigned short* Ab = A + (size_t)blockIdx.y * BM * lda;
  const unsigned short* Bb = B + (size_t)blockIdx.x * BN * ldb;

  const int frow = lane & 15, fk = (lane >> 4) << 3;

  f32x4 acc[TM][TN] = {};

  auto stage = [&](int ks, int bi) {
    const int k0 = ks << 5;
    #pragma unroll
    for (int r = 0; r < BM / 64; ++r) {
      int off16 = (r << 8) + t;
      int row = off16 >> 2, kk = (off16 & 3) << 3;
      gl_lds16(Ab + (size_t)row * lda + k0 + kk, &At[bi][(row << 5) + kk]);
    }
    #pragma unroll
    for (int r = 0; r < BN / 64; ++r) {
      int off16 = (r << 8) + t;
      int row = off16 >> 2, kk = (off16 & 3) << 3;
      gl_lds16(Bb + (size_t)row * ldb + k0 + kk, &Bt[bi][(row << 5) + kk]);
    }
  };

  stage(0, 0);

  for (int ks = 0; ks < kSteps; ++ks) {
    const int buf = ks & 1;
    __syncthreads();                        // drains prefetch for buf; prev reads done
    if (ks + 1 < kSteps) stage(ks + 1, buf ^ 1);

    bf16x8 af[TM], bv[TN];
    #pragma unroll
    for (int mi = 0; mi < TM; ++mi)
      af[mi] = *(const bf16x8*)&At[buf][((wm * (BM / 2) + mi * 16 + frow) << 5) + fk];
    #pragma unroll
    for (int ni = 0; ni < TN; ++ni)
      bv[ni] = *(const bf16x8*)&Bt[buf][((wn * (BN / 2) + ni * 16 + frow) << 5) + fk];
    #pragma unroll
    for (int mi = 0; mi < TM; ++mi)
      #pragma unroll
      for (int ni = 0; ni < TN; ++ni)
        acc[mi][ni] = __builtin_amdgcn_mfma_f32_16x16x32_bf16(af[mi], bv[ni], acc[mi][ni], 0, 0, 0);
  }

  // C/D layout (m89-verified): col = lane&15, row = (lane>>4)*4 + reg
  const int mb = blockIdx.y * BM + wm * (BM / 2) + ((lane >> 4) << 2);
  const int nb = blockIdx.x * BN + wn * (BN / 2) + (lane & 15);

  #pragma unroll
  for (int mi = 0; mi < TM; ++mi) {
    const int m = mb + mi * 16;
    #pragma unroll
    for (int ni = 0; ni < TN; ++ni) {
      const int n = nb + ni * 16;
      f32x4 v = acc[mi][ni];
      if constexpr (EPI == EPI_BIAS) {                 // bf16((acc + bias[n]) * scale)
        unsigned short* O = (unsigned short*)C0;
        const float bv2 = bias[n];
        #pragma unroll
        for (int r = 0; r < 4; ++r) O[(size_t)(m + r) * ldc + n] = f2bf((v[r] + bv2) * scale);
      } else if constexpr (EPI == EPI_DUAL) {          // out-proj: fp32 + bf16 copies
        float* Of = (float*)C0;
        unsigned short* Ob = (unsigned short*)C1;
        const float bv2 = bias[n];
        #pragma unroll
        for (int r = 0; r < 4; ++r) {
          const float x = v[r] + bv2;
          const size_t idx = (size_t)(m + r) * ldc + n;
          Of[idx] = x; Ob[idx] = f2bf(x);
        }
      } else if constexpr (EPI == EPI_RELU) {          // ff1: bf16(relu(acc+bias))
        unsigned short* O = (unsigned short*)C0;
        const float bv2 = bias[n];
        #pragma unroll
        for (int r = 0; r < 4; ++r) {
          const float x = v[r] + bv2;
          O[(size_t)(m + r) * ldc + n] = f2bf(x > 0.f ? x : 0.f);
        }
      } else if constexpr (EPI == EPI_RES) {           // ff2: fp32(acc+bias+resid)
        float* Of = (float*)C0;
        const float bv2 = bias[n];
        #pragma unroll
        for (int r = 0; r < 4; ++r) {
          const size_t idx = (size_t)(m + r) * ldc + n;
          Of[idx] = v[r] + bv2 + resid[idx];
        }
      }
    }
  }
}

// ---------- fused flash attention v4 ----------
// Q [8192][2048] bf16 (pre-scaled by log2(e)/16 => P = exp2(S), fixed-max
// softmax, no rescale). K [9216][2048] bf16, Vt [bh=128][d=256][li=576] bf16,
// X [8192][2048] bf16.
__global__ __launch_bounds__(512, 2)
void k_flash(const unsigned short* __restrict__ Q, const unsigned short* __restrict__ K,
             const unsigned short* __restrict__ Vt, unsigned short* __restrict__ X) {
  __shared__ unsigned short Ks[2][8 * 32 * 32];  // 16 KB x2  [kd8][li32][32]
  __shared__ unsigned short Vs[2][256 * 32];     // 16 KB x2  [d256][32li]
  __shared__ unsigned short Ps[256 * 40];        // 20 KB     [q256][li32] stride 40
  __shared__ unsigned short Ones[512];           //  1 KB     ones-column B-tile

  const int t = threadIdx.x, lane = t & 63, w = t >> 6;
  const int frow = lane & 15, quad = lane >> 4, fk = quad << 3;

  // XCD swizzle: id&7 = XCD; both q-blocks of one bh land on the same XCD
  const int id = blockIdx.x;
  const int qb = (id >> 3) & 1;
  const int bh = (id & 7) | ((id >> 4) << 3);
  const int b = bh >> 3, h = bh & 7;
  const int q0 = qb << 8;

  const unsigned short* Kg = K + ((size_t)b * 576) * 2048 + h * 256;
  const unsigned short* Vg = Vt + (size_t)bh * 147456;

  Ones[t] = (t < 32) ? (unsigned short)0x3F80 : (unsigned short)0;

  // Q fragments resident in VGPRs: wave w owns q rows q0+32w .. +31
  bf16x8 Qf[2][8];
  #pragma unroll
  for (int half = 0; half < 2; ++half) {
    const unsigned short* Qg =
        Q + ((size_t)(b * 512 + q0 + w * 32 + half * 16 + frow)) * 2048 + h * 256;
    #pragma unroll
    for (int kd = 0; kd < 8; ++kd)
      Qf[half][kd] = *(const bf16x8*)(Qg + kd * 32 + fk);
  }

  f32x4 acc_o[2][17] = {};   // [half][16 d-tiles + l]

  auto stage = [&](int s, int bi) {
    const int li0 = s << 5;
    unsigned short* Kb = &Ks[bi][0];
    unsigned short* Vb = &Vs[bi][0];
    #pragma unroll
    for (int it = 0; it < 2; ++it) {
      int e = (it << 9) + t;                    // 16B-chunk index, 0..1023
      int row = e >> 2, c = (e & 3) << 3;       // row = kd*32+li
      int kd = row >> 5, li = row & 31;
      gl_lds16(Kg + (size_t)(li0 + li) * 2048 + kd * 32 + c, &Kb[(row << 5) + c]);
    }
    #pragma unroll
    for (int it = 0; it < 2; ++it) {
      int e = (it << 9) + t;
      int d = e >> 2, c = (e & 3) << 3;
      gl_lds16(Vg + (size_t)d * 576 + li0 + c, &Vb[(d << 5) + c]);
    }
  };

  stage(0, 0);

  const int prow = (w << 5) + (quad << 2);     // Ps write row base (q within 256)

  for (int s = 0; s < 18; ++s) {
    const int buf = s & 1;
    __syncthreads();                 // drains vmcnt: buf(s) ready; prev consumed
    if (s + 1 < 18) stage(s + 1, buf ^ 1);

    // ---- S = Q_w @ K^T : 32 q x 32 li (K reads shared across halves) ----
    f32x4 acc_s[2][2] = {};
    #pragma unroll
    for (int kd = 0; kd < 8; ++kd) {
      #pragma unroll
      for (int ni = 0; ni < 2; ++ni) {
        const bf16x8 bv = *(const bf16x8*)&Ks[buf][((kd * 32 + ni * 16 + frow) << 5) + fk];
        acc_s[0][ni] = __builtin_amdgcn_mfma_f32_16x16x32_bf16(Qf[0][kd], bv, acc_s[0][ni], 0, 0, 0);
        acc_s[1][ni] = __builtin_amdgcn_mfma_f32_16x16x32_bf16(Qf[1][kd], bv, acc_s[1][ni], 0, 0, 0);
      }
    }

    // ---- P = exp2(S) (log2e folded into Q scale), write own Ps rows ----
    #pragma unroll
    for (int half = 0; half < 2; ++half)
      #pragma unroll
      for (int ni = 0; ni < 2; ++ni)
        #pragma unroll
        for (int r = 0; r < 4; ++r)
          Ps[(prow + half * 16 + r) * 40 + ni * 16 + frow] =
              f2bf(__builtin_amdgcn_exp2f(acc_s[half][ni][r]));

    // ---- O += P_w @ [V | 1]^T : 32q x 272d (V reads shared across halves) ----
    bf16x8 paf[2];
    paf[0] = *(const bf16x8*)&Ps[((w << 5) + frow) * 40 + fk];
    paf[1] = *(const bf16x8*)&Ps[((w << 5) + 16 + frow) * 40 + fk];
    #pragma unroll
    for (int ni = 0; ni < 16; ++ni) {
      const bf16x8 bv = *(const bf16x8*)&Vs[buf][((ni * 16 + frow) << 5) + fk];
      acc_o[0][ni] = __builtin_amdgcn_mfma_f32_16x16x32_bf16(paf[0], bv, acc_o[0][ni], 0, 0, 0);
      acc_o[1][ni] = __builtin_amdgcn_mfma_f32_16x16x32_bf16(paf[1], bv, acc_o[1][ni], 0, 0, 0);
    }
    {
      const bf16x8 bv = *(const bf16x8*)&Ones[(frow << 5) + fk];
      acc_o[0][16] = __builtin_amdgcn_mfma_f32_16x16x32_bf16(paf[0], bv, acc_o[0][16], 0, 0, 0);
      acc_o[1][16] = __builtin_amdgcn_mfma_f32_16x16x32_bf16(paf[1], bv, acc_o[1][16], 0, 0, 0);
    }
  }

  // ---- epilogue: l in acc_o[half][16] on lanes frow==0; broadcast in-quad ----
  #pragma unroll
  for (int half = 0; half < 2; ++half) {
    float linv[4];
    #pragma unroll
    for (int r = 0; r < 4; ++r)
      linv[r] = 1.0f / __shfl(acc_o[half][16][r], lane & 48);
    unsigned short* Xo = X + ((size_t)(b * 512 + q0 + w * 32 + half * 16 + (quad << 2))) * 2048 +
                         h * 256 + frow;
    #pragma unroll
    for (int ni = 0; ni < 16; ++ni)
      #pragma unroll
      for (int r = 0; r < 4; ++r)
        Xo[(size_t)r * 2048 + ni * 16] = f2bf(acc_o[half][ni][r] * linv[r]);
  }
}

// ---------- LayerNorm over 768, in place on fp32 rows ----------
__global__ __launch_bounds__(256) void k_layernorm768(float* O, const float* __restrict__ gamma,
                                                      const float* __restrict__ beta) {
  const int row = blockIdx.x;
  float* p = O + (size_t)row * 768;
  const int t = threadIdx.x;
  const int lane = t & 63, wave = t >> 6;
  const float x0 = p[t], x1 = p[t + 256], x2 = p[t + 512];
  float s = x0 + x1 + x2;
  float q = x0 * x0 + x1 * x1 + x2 * x2;
  #pragma unroll
  for (int i = 32; i >= 1; i >>= 1) { s += __shfl_xor(s, i); q += __shfl_xor(q, i); }
  __shared__ float rs[4], rq[4];
  if (lane == 0) { rs[wave] = s; rq[wave] = q; }
  __syncthreads();
  s = rs[0] + rs[1] + rs[2] + rs[3];
  q = rq[0] + rq[1] + rq[2] + rq[3];
  const float mu = s * (1.0f / 768.0f);
  const float var = q * (1.0f / 768.0f) - mu * mu;
  const float inv = rsqrtf(var + 1e-5f);
  p[t]       = (x0 - mu) * inv * gamma[t]       + beta[t];
  p[t + 256] = (x1 - mu) * inv * gamma[t + 256] + beta[t + 256];
  p[t + 512] = (x2 - mu) * inv * gamma[t + 512] + beta[t + 512];
}

// ---------- host ----------
extern "C" void kernel_launch(void* const* d_in, const int* in_sizes, int n_in,
                              void* d_out, int out_size, void* d_ws, size_t ws_size,
                              hipStream_t stream) {
  const float* text  = (const float*)d_in[0];
  const float* image = (const float*)d_in[1];
  const float* wq = (const float*)d_in[2];  const float* bq = (const float*)d_in[3];
  const float* wk = (const float*)d_in[4];  const float* bk = (const float*)d_in[5];
  const float* wv = (const float*)d_in[6];  const float* bv = (const float*)d_in[7];
  const float* wr = (const float*)d_in[8];  const float* br = (const float*)d_in[9];
  const float* w1 = (const float*)d_in[10]; const float* b1 = (const float*)d_in[11];
  const float* w2 = (const float*)d_in[12]; const float* b2 = (const float*)d_in[13];
  const float* gamma = (const float*)d_in[14]; const float* beta = (const float*)d_in[15];

  uint8_t* ws = (uint8_t*)d_ws;
  constexpr size_t o_Tbf = 0;
  constexpr size_t o_Ibf = 12582912;                 // 8192*768*2
  constexpr size_t o_X   = 0;                        // reuse region0 (disjoint lifetime)
  constexpr size_t o_Q   = 33554432;
  constexpr size_t o_Kb  = o_Q   + 33554432;         // 8192*2048*2
  constexpr size_t o_Vt  = o_Kb  + 37748736;         // 9216*2048*2
  constexpr size_t o_wqT = o_Vt  + 37748736;
  constexpr size_t o_wkT = o_wqT + 3145728;          // wkT: rows 0..2047 of fused B
  constexpr size_t o_wvT = o_wkT + 4194304;          // wvT: rows 2048..4095 (contiguous!)
  constexpr size_t o_wrT = o_wvT + 4194304;
  constexpr size_t o_w1T = o_wrT + 3145728;
  constexpr size_t o_w2T = o_w1T + 196608;
  constexpr size_t o_OutB= o_w2T + 196608;
  constexpr size_t o_H   = o_OutB+ 12582912;         // 8192*768*2

  unsigned short* Tbf  = (unsigned short*)(ws + o_Tbf);
  unsigned short* Ibf  = (unsigned short*)(ws + o_Ibf);
  unsigned short* Xb   = (unsigned short*)(ws + o_X);
  unsigned short* Qb   = (unsigned short*)(ws + o_Q);
  unsigned short* Kb   = (unsigned short*)(ws + o_Kb);
  unsigned short* Vt   = (unsigned short*)(ws + o_Vt);
  unsigned short* wqT  = (unsigned short*)(ws + o_wqT);
  unsigned short* wkT  = (unsigned short*)(ws + o_wkT);
  unsigned short* wvT  = (unsigned short*)(ws + o_wvT);
  unsigned short* wrT  = (unsigned short*)(ws + o_wrT);
  unsigned short* w1T  = (unsigned short*)(ws + o_w1T);
  unsigned short* w2T  = (unsigned short*)(ws + o_w2T);
  unsigned short* OutB = (unsigned short*)(ws + o_OutB);
  unsigned short* Hb   = (unsigned short*)(ws + o_H);
  float* OutF = (float*)d_out;

  const dim3 blk(256);

  // --- prep: convert inputs, transpose weights (fp32 -> bf16) ---
  k_f32_to_bf16<<<dim3(6144), blk, 0, stream>>>(text,  Tbf, 1572864);
  k_f32_to_bf16<<<dim3(9216), blk, 0, stream>>>(image, Ibf, 2359296);
  k_transpose_to_bf16<<<dim3(64, 24), blk, 0, stream>>>(wq, wqT, 768, 2048);
  k_transpose_to_bf16<<<dim3(64, 32), blk, 0, stream>>>(wk, wkT, 1024, 2048);
  k_transpose_to_bf16<<<dim3(64, 32), blk, 0, stream>>>(wv, wvT, 1024, 2048);
  k_transpose_to_bf16<<<dim3(24, 64), blk, 0, stream>>>(wr, wrT, 2048, 768);
  k_transpose_to_bf16<<<dim3(4, 24),  blk, 0, stream>>>(w1, w1T, 768, 128);
  k_transpose_to_bf16<<<dim3(24, 4),  blk, 0, stream>>>(w2, w2T, 128, 768);

  // --- Q = (text @ wq + bq) * log2(e)/16 : per-tile-barrier, grid 256 (1 round)
  k_gemm8<EPI_BIAS><<<dim3(8, 32), dim3(512), 0, stream>>>(
      Tbf, wqT, 768, 768, 12, Qb, nullptr, bq, nullptr, 2048, 0.0625f * 1.44269504f);
  // --- K|V fused: image @ [wk|wv] (wkT+wvT contiguous rows 0..4095) ---
  // grid 16x36 = 576 blocks (3 rounds at 1/CU) vs 2x288 (4 rounds).
  k_gemm8<EPI_KV><<<dim3(16, 36), dim3(512), 0, stream>>>(
      Ibf, wkT, 1024, 1024, 16, Kb, Vt, bk, bv, 2048, 1.0f);

  // --- fused attention: X = softmax(QK^T)V ---
  k_flash<<<dim3(256), dim3(512), 0, stream>>>(Qb, Kb, Vt, Xb);

  // --- out = X @ wr + br : fp32 into d_out + bf16 copy for FF ---
  k_gemm<128, 128, EPI_DUAL><<<dim3(6, 64), blk, 0, stream>>>(
      Xb, wrT, 2048, 2048, 64, OutF, OutB, br, nullptr, 768, 1.0f);

  // --- h = relu(out @ w1 + b1) : [8192,128], 64x64 tiles for 256 blocks ---
  k_gemm<64, 64, EPI_RELU><<<dim3(2, 128), blk, 0, stream>>>(
      OutB, w1T, 768, 768, 24, Hb, nullptr, b1, nullptr, 128, 1.0f);

  // --- out += h @ w2 + b2 (residual from d_out) ---
  k_gemm<128, 128, EPI_RES><<<dim3(6, 64), blk, 0, stream>>>(
      Hb, w2T, 128, 128, 4, OutF, nullptr, b2, (const float*)d_out, 768, 1.0f);

  // --- LayerNorm in place on d_out ---
  k_layernorm768<<<dim3(8192), blk, 0, stream>>>(OutF, gamma, beta);

  (void)in_sizes; (void)n_in; (void)out_size; (void)ws_size;
}

// Round 7
// 455.031 us; speedup vs baseline: 1.0389x; 1.0389x over previous
//
#include <hip/hip_runtime.h>
#include <stdint.h>
#include <stddef.h>

// ---------- types / helpers ----------
typedef __attribute__((ext_vector_type(8))) short bf16x8;   // 8 bf16 in 4 VGPRs
typedef __attribute__((ext_vector_type(4))) float f32x4;

typedef __attribute__((address_space(1))) unsigned int uint_g;
typedef __attribute__((address_space(3))) unsigned int uint_l;

#define DEV static __device__ __forceinline__

DEV unsigned short f2bf(float f) {          // RNE float -> bf16 bits
  unsigned int u = __float_as_uint(f);
  u += 0x7FFFu + ((u >> 16) & 1u);
  return (unsigned short)(u >> 16);
}

DEV void gl_lds16(const unsigned short* g, unsigned short* l) {
  // async global->LDS, 16B per lane; LDS dest = wave-uniform base + lane*16
  __builtin_amdgcn_global_load_lds((const uint_g*)g, (uint_l*)l, 16, 0, 0);
}

// ---------- elementwise f32 -> bf16 (vectorized x4) ----------
__global__ __launch_bounds__(256) void k_f32_to_bf16(const float* __restrict__ in,
                                                     unsigned short* __restrict__ out, int n4) {
  int i = blockIdx.x * 256 + threadIdx.x;
  if (i >= n4) return;
  const float4 v = ((const float4*)in)[i];
  ushort4 o;
  o.x = f2bf(v.x); o.y = f2bf(v.y); o.z = f2bf(v.z); o.w = f2bf(v.w);
  ((ushort4*)out)[i] = o;
}

// ---------- transpose fp32 [R][C] -> bf16 [C][R] ----------
__global__ __launch_bounds__(256) void k_transpose_to_bf16(const float* __restrict__ in,
                                                           unsigned short* __restrict__ out,
                                                           int R, int C) {
  __shared__ unsigned short tile[32][33];   // +1 pad breaks bank conflicts
  const int c0 = blockIdx.x << 5, r0 = blockIdx.y << 5;
  const int tx = threadIdx.x & 31, ty = threadIdx.x >> 5;   // 32x8
  #pragma unroll
  for (int i = 0; i < 32; i += 8)
    tile[ty + i][tx] = f2bf(in[(size_t)(r0 + ty + i) * C + c0 + tx]);
  __syncthreads();
  #pragma unroll
  for (int i = 0; i < 32; i += 8)
    out[(size_t)(c0 + ty + i) * R + r0 + tx] = tile[tx][ty + i];
}

enum { EPI_BIAS = 0, EPI_VT = 3, EPI_DUAL = 4, EPI_RELU = 5, EPI_RES = 6, EPI_KV = 7 };

// ---------- 8-phase 256x256 bf16 GEMM body (r5 schedule, best measured) ----
// All ds_reads issue PRE-barrier (fresh-tile p0 reads legal: tile certified
// at the PREVIOUS tile's p3 vmcnt). One half-tile staged per phase:
//   p0 -> (kt+1)A1, p1 -> (kt+2)B0, p2 -> (kt+2)B1, p3 -> (kt+2)A0
// vmcnt(6) at p3 (after issue) certifies all of tile kt+1 and keeps the
// 3-half in-flight invariant. Tail: vmcnt(0) at kTiles-2's p3. 2 raw
// s_barriers/phase, never vmcnt(0) in steady state. T2 swizzle:
// LDS[row][c16] = G[row][c16 ^ (row&7)], gl_lds dest linear (rule #21).
// Refactored into a __device__ body (LDS passed in) so the fused QKV kernel
// can run two GEMM configs from one dispatch pool (kills the 1-block/CU
// grid-quantization bubble: 576-block KV = 3 rounds for 2.25 rounds of work;
// the 256 Q blocks now backfill that 0.75-round hole).
template <int EPI>
DEV void gemm8_body(unsigned short (&As)[2][16384], unsigned short (&Bs)[2][16384],
                    const unsigned short* __restrict__ A, const unsigned short* __restrict__ B,
                    int lda, int ldb, int kTiles,
                    void* C0, void* C1, const float* bias, const float* bias2,
                    int ldc, float scale, int bx, int by) {
  const int t = threadIdx.x;
  const int lane = t & 63, w = t >> 6;
  const int wm = w >> 2, wn = w & 3;           // 2M x 4N wave grid
  const int frow = lane & 15, quad = lane >> 4;

  const unsigned short* Ab = A + (size_t)by * 256 * lda;
  const unsigned short* Bb = B + (size_t)bx * 256 * ldb;

  f32x4 acc[8][4] = {};

  auto stA = [&](int kt, int bi, int h) {
    #pragma unroll
    for (int it = 0; it < 2; ++it) {
      int e = (it << 9) + t;
      int row = (h << 7) + (e >> 3);
      int c16 = (e & 7) ^ (row & 7);
      gl_lds16(Ab + (size_t)row * lda + (kt << 6) + (c16 << 3),
               &As[bi][(row << 6) + ((e & 7) << 3)]);
    }
  };
  auto stB = [&](int kt, int bi, int h) {
    #pragma unroll
    for (int it = 0; it < 2; ++it) {
      int e = (it << 9) + t;
      int row = (h << 7) + (e >> 3);
      int c16 = (e & 7) ^ (row & 7);
      gl_lds16(Bb + (size_t)row * ldb + (kt << 6) + (c16 << 3),
               &Bs[bi][(row << 6) + ((e & 7) << 3)]);
    }
  };
  auto frag = [&](const unsigned short* buf, int row, int ksl) -> bf16x8 {
    int col = ((ksl << 5) + (quad << 3)) ^ ((row & 7) << 3);
    return *(const bf16x8*)&buf[(row << 6) + col];
  };

  // prologue -- FIFO: 0:B0,0:B1,0:A0,0:A1, 1:B0,1:B1,1:A0 (14 loads);
  // vmcnt(6) certifies tile0 (8 oldest), leaves {1:B0,B1,A0} = invariant.
  stB(0, 0, 0); stB(0, 0, 1); stA(0, 0, 0); stA(0, 0, 1);
  if (kTiles > 1) {
    stB(1, 1, 0); stB(1, 1, 1); stA(1, 1, 0);
    asm volatile("s_waitcnt vmcnt(6)" ::: "memory");
  } else {
    asm volatile("s_waitcnt vmcnt(0)" ::: "memory");
  }
  asm volatile("s_barrier" ::: "memory");      // cross-wave: tile0 visible

  bf16x8 a[4][2], b0[2][2], b1[2][2];
  const int arow = wm << 7, brow = wn << 6;

  for (int kt = 0; kt < kTiles; ++kt) {
    const int pb = kt & 1, qb = pb ^ 1;
    const unsigned short* Ac = As[pb];
    const unsigned short* Bc = Bs[pb];

    // ---- phase 0 : (mh0, nh0); reads PRE-barrier; stage (kt+1)A1 -> qb
    #pragma unroll
    for (int m = 0; m < 4; ++m)
      #pragma unroll
      for (int k = 0; k < 2; ++k) a[m][k] = frag(Ac, arow + (m << 4) + frow, k);
    #pragma unroll
    for (int n = 0; n < 2; ++n)
      #pragma unroll
      for (int k = 0; k < 2; ++k) b0[n][k] = frag(Bc, brow + (n << 4) + frow, k);
    if (kt + 1 < kTiles) stA(kt + 1, qb, 1);
    asm volatile("s_barrier" ::: "memory");
    asm volatile("s_waitcnt lgkmcnt(0)" ::: "memory");
    __builtin_amdgcn_s_setprio(1);
    #pragma unroll
    for (int m = 0; m < 4; ++m)
      #pragma unroll
      for (int n = 0; n < 2; ++n)
        #pragma unroll
        for (int k = 0; k < 2; ++k)
          acc[m][n] = __builtin_amdgcn_mfma_f32_16x16x32_bf16(a[m][k], b0[n][k], acc[m][n], 0, 0, 0);
    __builtin_amdgcn_s_setprio(0);
    asm volatile("s_barrier" ::: "memory");

    // ---- phase 1 : (mh0, nh1); stage (kt+2)B0 -> pb (B0 last read @p0)
    #pragma unroll
    for (int n = 0; n < 2; ++n)
      #pragma unroll
      for (int k = 0; k < 2; ++k) b1[n][k] = frag(Bc, brow + 32 + (n << 4) + frow, k);
    if (kt + 2 < kTiles) stB(kt + 2, pb, 0);
    asm volatile("s_barrier" ::: "memory");
    asm volatile("s_waitcnt lgkmcnt(0)" ::: "memory");
    __builtin_amdgcn_s_setprio(1);
    #pragma unroll
    for (int m = 0; m < 4; ++m)
      #pragma unroll
      for (int n = 0; n < 2; ++n)
        #pragma unroll
        for (int k = 0; k < 2; ++k)
          acc[m][2 + n] = __builtin_amdgcn_mfma_f32_16x16x32_bf16(a[m][k], b1[n][k], acc[m][2 + n], 0, 0, 0);
    __builtin_amdgcn_s_setprio(0);
    asm volatile("s_barrier" ::: "memory");

    // ---- phase 2 : (mh1, nh0); refill A regs; stage (kt+2)B1 (read @p1)
    #pragma unroll
    for (int m = 0; m < 4; ++m)
      #pragma unroll
      for (int k = 0; k < 2; ++k) a[m][k] = frag(Ac, arow + 64 + (m << 4) + frow, k);
    if (kt + 2 < kTiles) stB(kt + 2, pb, 1);
    asm volatile("s_barrier" ::: "memory");
    asm volatile("s_waitcnt lgkmcnt(0)" ::: "memory");
    __builtin_amdgcn_s_setprio(1);
    #pragma unroll
    for (int m = 0; m < 4; ++m)
      #pragma unroll
      for (int n = 0; n < 2; ++n)
        #pragma unroll
        for (int k = 0; k < 2; ++k)
          acc[4 + m][n] = __builtin_amdgcn_mfma_f32_16x16x32_bf16(a[m][k], b0[n][k], acc[4 + m][n], 0, 0, 0);
    __builtin_amdgcn_s_setprio(0);
    asm volatile("s_barrier" ::: "memory");

    // ---- phase 3 : (mh1, nh1); stage (kt+2)A0 (read @p0); certify kt+1
    if (kt + 2 < kTiles) {
      stA(kt + 2, pb, 0);
      asm volatile("s_waitcnt vmcnt(6)" ::: "memory");   // tile kt+1 resident
    } else if (kt + 1 < kTiles) {
      asm volatile("s_waitcnt vmcnt(0)" ::: "memory");   // last tile resident
    }
    asm volatile("s_barrier" ::: "memory");
    __builtin_amdgcn_s_setprio(1);
    #pragma unroll
    for (int m = 0; m < 4; ++m)
      #pragma unroll
      for (int n = 0; n < 2; ++n)
        #pragma unroll
        for (int k = 0; k < 2; ++k)
          acc[4 + m][2 + n] = __builtin_amdgcn_mfma_f32_16x16x32_bf16(a[m][k], b1[n][k], acc[4 + m][2 + n], 0, 0, 0);
    __builtin_amdgcn_s_setprio(0);
    asm volatile("s_barrier" ::: "memory");
  }

  // ---- epilogue: C/D layout col=lane&15, row=(lane>>4)*4+reg ----
  const int mb = by * 256 + wm * 128 + (quad << 2);
  const int nb = bx * 256 + wn * 64 + frow;
  #pragma unroll
  for (int mi = 0; mi < 8; ++mi) {
    const int m = mb + mi * 16;
    #pragma unroll
    for (int ni = 0; ni < 4; ++ni) {
      const int n = nb + ni * 16;
      f32x4 v = acc[mi][ni];
      if constexpr (EPI == EPI_BIAS) {
        unsigned short* O = (unsigned short*)C0;
        const float bv2 = bias[n];
        #pragma unroll
        for (int r = 0; r < 4; ++r) O[(size_t)(m + r) * ldc + n] = f2bf((v[r] + bv2) * scale);
      } else if constexpr (EPI == EPI_KV) {
        if (n < 2048) {                                  // K path (uniform per block)
          unsigned short* O = (unsigned short*)C0;
          const float bv2 = bias[n];
          #pragma unroll
          for (int r = 0; r < 4; ++r) O[(size_t)(m + r) * ldc + n] = f2bf(v[r] + bv2);
        } else {                                         // V path -> Vt[b][h][d][li]
          const int n2 = n - 2048;
          const int b = m / 576, li = m - b * 576;
          const int h = n2 >> 8, d = n2 & 255;
          const float bv2 = bias2[n2];
          ushort4 o;
          o.x = f2bf(v[0] + bv2); o.y = f2bf(v[1] + bv2);
          o.z = f2bf(v[2] + bv2); o.w = f2bf(v[3] + bv2);
          *(ushort4*)((unsigned short*)C1 + ((size_t)((b * 8 + h) * 256 + d)) * 576 + li) = o;
        }
      }
    }
  }
}

// ---------- fused Q + K|V projection: one dispatch pool, 832 blocks -------
// ids 0..575  : KV GEMM  image @ [wk|wv]^T  (16 cols x 36 rows, 16 K-tiles)
// ids 576..831: Q  GEMM  text  @ wq^T       (8 cols x 32 rows, 12 K-tiles)
// Long blocks first: the work-conserving dispatcher backfills KV's partial
// last round with the (shorter) Q blocks instead of idling 192 CUs.
__global__ __launch_bounds__(512, 2)
void k_qkv(const unsigned short* __restrict__ Tbf, const unsigned short* __restrict__ wqT,
           unsigned short* Qb, const float* bq, float qscale,
           const unsigned short* __restrict__ Ibf, const unsigned short* __restrict__ wkT,
           unsigned short* Kb, unsigned short* Vt, const float* bk, const float* bv) {
  __shared__ unsigned short As[2][16384];   // 64 KB
  __shared__ unsigned short Bs[2][16384];   // 64 KB
  const int id = blockIdx.x;
  if (id < 576) {
    gemm8_body<EPI_KV>(As, Bs, Ibf, wkT, 1024, 1024, 16,
                       Kb, Vt, bk, bv, 2048, 1.0f, id & 15, id >> 4);
  } else {
    const int q = id - 576;
    gemm8_body<EPI_BIAS>(As, Bs, Tbf, wqT, 768, 768, 12,
                         Qb, nullptr, bq, nullptr, 2048, qscale, q & 7, q >> 3);
  }
}

// ---------- generic bf16 MFMA GEMM: C = A @ B^T (+epilogue) ----------
// round-0 form (best 2-phase measured): single-barrier double-buffered K-loop.
// Used for out-proj / ff1 / ff2 (shapes that don't fit 256x256 tiling).
template <int BM, int BN, int EPI>
__global__ __launch_bounds__(256)
void k_gemm(const unsigned short* __restrict__ A, const unsigned short* __restrict__ B,
            int lda, int ldb, int kSteps,
            void* C0, void* C1, const float* bias, const float* resid, int ldc, float scale) {
  constexpr int TM = BM / 32;
  constexpr int TN = BN / 32;
  __shared__ unsigned short At[2][BM * 32];
  __shared__ unsigned short Bt[2][BN * 32];

  const int t = threadIdx.x;
  const int lane = t & 63, wave = t >> 6;
  const int wm = wave >> 1, wn = wave & 1;            // 2x2 wave grid

  const unsigned short* Ab = A + (size_t)blockIdx.y * BM * lda;
  const unsigned short* Bb = B + (size_t)blockIdx.x * BN * ldb;

  const int frow = lane & 15, fk = (lane >> 4) << 3;

  f32x4 acc[TM][TN] = {};

  auto stage = [&](int ks, int bi) {
    const int k0 = ks << 5;
    #pragma unroll
    for (int r = 0; r < BM / 64; ++r) {
      int off16 = (r << 8) + t;
      int row = off16 >> 2, kk = (off16 & 3) << 3;
      gl_lds16(Ab + (size_t)row * lda + k0 + kk, &At[bi][(row << 5) + kk]);
    }
    #pragma unroll
    for (int r = 0; r < BN / 64; ++r) {
      int off16 = (r << 8) + t;
      int row = off16 >> 2, kk = (off16 & 3) << 3;
      gl_lds16(Bb + (size_t)row * ldb + k0 + kk, &Bt[bi][(row << 5) + kk]);
    }
  };

  stage(0, 0);

  for (int ks = 0; ks < kSteps; ++ks) {
    const int buf = ks & 1;
    __syncthreads();                        // drains prefetch for buf; prev reads done
    if (ks + 1 < kSteps) stage(ks + 1, buf ^ 1);

    bf16x8 af[TM], bv[TN];
    #pragma unroll
    for (int mi = 0; mi < TM; ++mi)
      af[mi] = *(const bf16x8*)&At[buf][((wm * (BM / 2) + mi * 16 + frow) << 5) + fk];
    #pragma unroll
    for (int ni = 0; ni < TN; ++ni)
      bv[ni] = *(const bf16x8*)&Bt[buf][((wn * (BN / 2) + ni * 16 + frow) << 5) + fk];
    #pragma unroll
    for (int mi = 0; mi < TM; ++mi)
      #pragma unroll
      for (int ni = 0; ni < TN; ++ni)
        acc[mi][ni] = __builtin_amdgcn_mfma_f32_16x16x32_bf16(af[mi], bv[ni], acc[mi][ni], 0, 0, 0);
  }

  // C/D layout (m89-verified): col = lane&15, row = (lane>>4)*4 + reg
  const int mb = blockIdx.y * BM + wm * (BM / 2) + ((lane >> 4) << 2);
  const int nb = blockIdx.x * BN + wn * (BN / 2) + (lane & 15);

  #pragma unroll
  for (int mi = 0; mi < TM; ++mi) {
    const int m = mb + mi * 16;
    #pragma unroll
    for (int ni = 0; ni < TN; ++ni) {
      const int n = nb + ni * 16;
      f32x4 v = acc[mi][ni];
      if constexpr (EPI == EPI_BIAS) {                 // bf16((acc + bias[n]) * scale)
        unsigned short* O = (unsigned short*)C0;
        const float bv2 = bias[n];
        #pragma unroll
        for (int r = 0; r < 4; ++r) O[(size_t)(m + r) * ldc + n] = f2bf((v[r] + bv2) * scale);
      } else if constexpr (EPI == EPI_DUAL) {          // out-proj: fp32 + bf16 copies
        float* Of = (float*)C0;
        unsigned short* Ob = (unsigned short*)C1;
        const float bv2 = bias[n];
        #pragma unroll
        for (int r = 0; r < 4; ++r) {
          const float x = v[r] + bv2;
          const size_t idx = (size_t)(m + r) * ldc + n;
          Of[idx] = x; Ob[idx] = f2bf(x);
        }
      } else if constexpr (EPI == EPI_RELU) {          // ff1: bf16(relu(acc+bias))
        unsigned short* O = (unsigned short*)C0;
        const float bv2 = bias[n];
        #pragma unroll
        for (int r = 0; r < 4; ++r) {
          const float x = v[r] + bv2;
          O[(size_t)(m + r) * ldc + n] = f2bf(x > 0.f ? x : 0.f);
        }
      } else if constexpr (EPI == EPI_RES) {           // ff2: fp32(acc+bias+resid)
        float* Of = (float*)C0;
        const float bv2 = bias[n];
        #pragma unroll
        for (int r = 0; r < 4; ++r) {
          const size_t idx = (size_t)(m + r) * ldc + n;
          Of[idx] = v[r] + bv2 + resid[idx];
        }
      }
    }
  }
}

// ---------- fused flash attention v4 ----------
// Q [8192][2048] bf16 (pre-scaled by log2(e)/16 => P = exp2(S), fixed-max
// softmax, no rescale). K [9216][2048] bf16, Vt [bh=128][d=256][li=576] bf16,
// X [8192][2048] bf16.
__global__ __launch_bounds__(512, 2)
void k_flash(const unsigned short* __restrict__ Q, const unsigned short* __restrict__ K,
             const unsigned short* __restrict__ Vt, unsigned short* __restrict__ X) {
  __shared__ unsigned short Ks[2][8 * 32 * 32];  // 16 KB x2  [kd8][li32][32]
  __shared__ unsigned short Vs[2][256 * 32];     // 16 KB x2  [d256][32li]
  __shared__ unsigned short Ps[256 * 40];        // 20 KB     [q256][li32] stride 40
  __shared__ unsigned short Ones[512];           //  1 KB     ones-column B-tile

  const int t = threadIdx.x, lane = t & 63, w = t >> 6;
  const int frow = lane & 15, quad = lane >> 4, fk = quad << 3;

  // XCD swizzle: id&7 = XCD; both q-blocks of one bh land on the same XCD
  const int id = blockIdx.x;
  const int qb = (id >> 3) & 1;
  const int bh = (id & 7) | ((id >> 4) << 3);
  const int b = bh >> 3, h = bh & 7;
  const int q0 = qb << 8;

  const unsigned short* Kg = K + ((size_t)b * 576) * 2048 + h * 256;
  const unsigned short* Vg = Vt + (size_t)bh * 147456;

  Ones[t] = (t < 32) ? (unsigned short)0x3F80 : (unsigned short)0;

  // Q fragments resident in VGPRs: wave w owns q rows q0+32w .. +31
  bf16x8 Qf[2][8];
  #pragma unroll
  for (int half = 0; half < 2; ++half) {
    const unsigned short* Qg =
        Q + ((size_t)(b * 512 + q0 + w * 32 + half * 16 + frow)) * 2048 + h * 256;
    #pragma unroll
    for (int kd = 0; kd < 8; ++kd)
      Qf[half][kd] = *(const bf16x8*)(Qg + kd * 32 + fk);
  }

  f32x4 acc_o[2][17] = {};   // [half][16 d-tiles + l]

  auto stage = [&](int s, int bi) {
    const int li0 = s << 5;
    unsigned short* Kb = &Ks[bi][0];
    unsigned short* Vb = &Vs[bi][0];
    #pragma unroll
    for (int it = 0; it < 2; ++it) {
      int e = (it << 9) + t;                    // 16B-chunk index, 0..1023
      int row = e >> 2, c = (e & 3) << 3;       // row = kd*32+li
      int kd = row >> 5, li = row & 31;
      gl_lds16(Kg + (size_t)(li0 + li) * 2048 + kd * 32 + c, &Kb[(row << 5) + c]);
    }
    #pragma unroll
    for (int it = 0; it < 2; ++it) {
      int e = (it << 9) + t;
      int d = e >> 2, c = (e & 3) << 3;
      gl_lds16(Vg + (size_t)d * 576 + li0 + c, &Vb[(d << 5) + c]);
    }
  };

  stage(0, 0);

  const int prow = (w << 5) + (quad << 2);     // Ps write row base (q within 256)

  for (int s = 0; s < 18; ++s) {
    const int buf = s & 1;
    __syncthreads();                 // drains vmcnt: buf(s) ready; prev consumed
    if (s + 1 < 18) stage(s + 1, buf ^ 1);

    // ---- S = Q_w @ K^T : 32 q x 32 li (K reads shared across halves) ----
    f32x4 acc_s[2][2] = {};
    #pragma unroll
    for (int kd = 0; kd < 8; ++kd) {
      #pragma unroll
      for (int ni = 0; ni < 2; ++ni) {
        const bf16x8 bv = *(const bf16x8*)&Ks[buf][((kd * 32 + ni * 16 + frow) << 5) + fk];
        acc_s[0][ni] = __builtin_amdgcn_mfma_f32_16x16x32_bf16(Qf[0][kd], bv, acc_s[0][ni], 0, 0, 0);
        acc_s[1][ni] = __builtin_amdgcn_mfma_f32_16x16x32_bf16(Qf[1][kd], bv, acc_s[1][ni], 0, 0, 0);
      }
    }

    // ---- P = exp2(S) (log2e folded into Q scale), write own Ps rows ----
    #pragma unroll
    for (int half = 0; half < 2; ++half)
      #pragma unroll
      for (int ni = 0; ni < 2; ++ni)
        #pragma unroll
        for (int r = 0; r < 4; ++r)
          Ps[(prow + half * 16 + r) * 40 + ni * 16 + frow] =
              f2bf(__builtin_amdgcn_exp2f(acc_s[half][ni][r]));

    // ---- O += P_w @ [V | 1]^T : 32q x 272d (V reads shared across halves) ----
    bf16x8 paf[2];
    paf[0] = *(const bf16x8*)&Ps[((w << 5) + frow) * 40 + fk];
    paf[1] = *(const bf16x8*)&Ps[((w << 5) + 16 + frow) * 40 + fk];
    #pragma unroll
    for (int ni = 0; ni < 16; ++ni) {
      const bf16x8 bv = *(const bf16x8*)&Vs[buf][((ni * 16 + frow) << 5) + fk];
      acc_o[0][ni] = __builtin_amdgcn_mfma_f32_16x16x32_bf16(paf[0], bv, acc_o[0][ni], 0, 0, 0);
      acc_o[1][ni] = __builtin_amdgcn_mfma_f32_16x16x32_bf16(paf[1], bv, acc_o[1][ni], 0, 0, 0);
    }
    {
      const bf16x8 bv = *(const bf16x8*)&Ones[(frow << 5) + fk];
      acc_o[0][16] = __builtin_amdgcn_mfma_f32_16x16x32_bf16(paf[0], bv, acc_o[0][16], 0, 0, 0);
      acc_o[1][16] = __builtin_amdgcn_mfma_f32_16x16x32_bf16(paf[1], bv, acc_o[1][16], 0, 0, 0);
    }
  }

  // ---- epilogue: l in acc_o[half][16] on lanes frow==0; broadcast in-quad ----
  #pragma unroll
  for (int half = 0; half < 2; ++half) {
    float linv[4];
    #pragma unroll
    for (int r = 0; r < 4; ++r)
      linv[r] = 1.0f / __shfl(acc_o[half][16][r], lane & 48);
    unsigned short* Xo = X + ((size_t)(b * 512 + q0 + w * 32 + half * 16 + (quad << 2))) * 2048 +
                         h * 256 + frow;
    #pragma unroll
    for (int ni = 0; ni < 16; ++ni)
      #pragma unroll
      for (int r = 0; r < 4; ++r)
        Xo[(size_t)r * 2048 + ni * 16] = f2bf(acc_o[half][ni][r] * linv[r]);
  }
}

// ---------- LayerNorm over 768, in place on fp32 rows ----------
__global__ __launch_bounds__(256) void k_layernorm768(float* O, const float* __restrict__ gamma,
                                                      const float* __restrict__ beta) {
  const int row = blockIdx.x;
  float* p = O + (size_t)row * 768;
  const int t = threadIdx.x;
  const int lane = t & 63, wave = t >> 6;
  const float x0 = p[t], x1 = p[t + 256], x2 = p[t + 512];
  float s = x0 + x1 + x2;
  float q = x0 * x0 + x1 * x1 + x2 * x2;
  #pragma unroll
  for (int i = 32; i >= 1; i >>= 1) { s += __shfl_xor(s, i); q += __shfl_xor(q, i); }
  __shared__ float rs[4], rq[4];
  if (lane == 0) { rs[wave] = s; rq[wave] = q; }
  __syncthreads();
  s = rs[0] + rs[1] + rs[2] + rs[3];
  q = rq[0] + rq[1] + rq[2] + rq[3];
  const float mu = s * (1.0f / 768.0f);
  const float var = q * (1.0f / 768.0f) - mu * mu;
  const float inv = rsqrtf(var + 1e-5f);
  p[t]       = (x0 - mu) * inv * gamma[t]       + beta[t];
  p[t + 256] = (x1 - mu) * inv * gamma[t + 256] + beta[t + 256];
  p[t + 512] = (x2 - mu) * inv * gamma[t + 512] + beta[t + 512];
}

// ---------- host ----------
extern "C" void kernel_launch(void* const* d_in, const int* in_sizes, int n_in,
                              void* d_out, int out_size, void* d_ws, size_t ws_size,
                              hipStream_t stream) {
  const float* text  = (const float*)d_in[0];
  const float* image = (const float*)d_in[1];
  const float* wq = (const float*)d_in[2];  const float* bq = (const float*)d_in[3];
  const float* wk = (const float*)d_in[4];  const float* bk = (const float*)d_in[5];
  const float* wv = (const float*)d_in[6];  const float* bv = (const float*)d_in[7];
  const float* wr = (const float*)d_in[8];  const float* br = (const float*)d_in[9];
  const float* w1 = (const float*)d_in[10]; const float* b1 = (const float*)d_in[11];
  const float* w2 = (const float*)d_in[12]; const float* b2 = (const float*)d_in[13];
  const float* gamma = (const float*)d_in[14]; const float* beta = (const float*)d_in[15];

  uint8_t* ws = (uint8_t*)d_ws;
  constexpr size_t o_Tbf = 0;
  constexpr size_t o_Ibf = 12582912;                 // 8192*768*2
  constexpr size_t o_X   = 0;                        // reuse region0 (disjoint lifetime)
  constexpr size_t o_Q   = 33554432;
  constexpr size_t o_Kb  = o_Q   + 33554432;         // 8192*2048*2
  constexpr size_t o_Vt  = o_Kb  + 37748736;         // 9216*2048*2
  constexpr size_t o_wqT = o_Vt  + 37748736;
  constexpr size_t o_wkT = o_wqT + 3145728;          // wkT: rows 0..2047 of fused B
  constexpr size_t o_wvT = o_wkT + 4194304;          // wvT: rows 2048..4095 (contiguous!)
  constexpr size_t o_wrT = o_wvT + 4194304;
  constexpr size_t o_w1T = o_wrT + 3145728;
  constexpr size_t o_w2T = o_w1T + 196608;
  constexpr size_t o_OutB= o_w2T + 196608;
  constexpr size_t o_H   = o_OutB+ 12582912;         // 8192*768*2

  unsigned short* Tbf  = (unsigned short*)(ws + o_Tbf);
  unsigned short* Ibf  = (unsigned short*)(ws + o_Ibf);
  unsigned short* Xb   = (unsigned short*)(ws + o_X);
  unsigned short* Qb   = (unsigned short*)(ws + o_Q);
  unsigned short* Kb   = (unsigned short*)(ws + o_Kb);
  unsigned short* Vt   = (unsigned short*)(ws + o_Vt);
  unsigned short* wqT  = (unsigned short*)(ws + o_wqT);
  unsigned short* wkT  = (unsigned short*)(ws + o_wkT);
  unsigned short* wvT  = (unsigned short*)(ws + o_wvT);
  unsigned short* wrT  = (unsigned short*)(ws + o_wrT);
  unsigned short* w1T  = (unsigned short*)(ws + o_w1T);
  unsigned short* w2T  = (unsigned short*)(ws + o_w2T);
  unsigned short* OutB = (unsigned short*)(ws + o_OutB);
  unsigned short* Hb   = (unsigned short*)(ws + o_H);
  float* OutF = (float*)d_out;

  const dim3 blk(256);

  // --- prep: convert inputs, transpose weights (fp32 -> bf16) ---
  k_f32_to_bf16<<<dim3(6144), blk, 0, stream>>>(text,  Tbf, 1572864);
  k_f32_to_bf16<<<dim3(9216), blk, 0, stream>>>(image, Ibf, 2359296);
  k_transpose_to_bf16<<<dim3(64, 24), blk, 0, stream>>>(wq, wqT, 768, 2048);
  k_transpose_to_bf16<<<dim3(64, 32), blk, 0, stream>>>(wk, wkT, 1024, 2048);
  k_transpose_to_bf16<<<dim3(64, 32), blk, 0, stream>>>(wv, wvT, 1024, 2048);
  k_transpose_to_bf16<<<dim3(24, 64), blk, 0, stream>>>(wr, wrT, 2048, 768);
  k_transpose_to_bf16<<<dim3(4, 24),  blk, 0, stream>>>(w1, w1T, 768, 128);
  k_transpose_to_bf16<<<dim3(24, 4),  blk, 0, stream>>>(w2, w2T, 128, 768);

  // --- fused Q + K|V projections: one 832-block pool (KV first, Q backfills)
  k_qkv<<<dim3(832), dim3(512), 0, stream>>>(
      Tbf, wqT, Qb, bq, 0.0625f * 1.44269504f,
      Ibf, wkT, Kb, Vt, bk, bv);

  // --- fused attention: X = softmax(QK^T)V ---
  k_flash<<<dim3(256), dim3(512), 0, stream>>>(Qb, Kb, Vt, Xb);

  // --- out = X @ wr + br : fp32 into d_out + bf16 copy for FF ---
  k_gemm<128, 128, EPI_DUAL><<<dim3(6, 64), blk, 0, stream>>>(
      Xb, wrT, 2048, 2048, 64, OutF, OutB, br, nullptr, 768, 1.0f);

  // --- h = relu(out @ w1 + b1) : [8192,128], 64x64 tiles for 256 blocks ---
  k_gemm<64, 64, EPI_RELU><<<dim3(2, 128), blk, 0, stream>>>(
      OutB, w1T, 768, 768, 24, Hb, nullptr, b1, nullptr, 128, 1.0f);

  // --- out += h @ w2 + b2 (residual from d_out) ---
  k_gemm<128, 128, EPI_RES><<<dim3(6, 64), blk, 0, stream>>>(
      Hb, w2T, 128, 128, 4, OutF, nullptr, b2, (const float*)d_out, 768, 1.0f);

  // --- LayerNorm in place on d_out ---
  k_layernorm768<<<dim3(8192), blk, 0, stream>>>(OutF, gamma, beta);

  (void)in_sizes; (void)n_in; (void)out_size; (void)ws_size;
}

// Round 8
// 425.627 us; speedup vs baseline: 1.1107x; 1.0691x over previous
//
#include <hip/hip_runtime.h>
#include <stdint.h>
#include <stddef.h>

// ---------- types / helpers ----------
typedef __attribute__((ext_vector_type(8))) short bf16x8;   // 8 bf16 in 4 VGPRs
typedef __attribute__((ext_vector_type(4))) float f32x4;

typedef __attribute__((address_space(1))) unsigned int uint_g;
typedef __attribute__((address_space(3))) unsigned int uint_l;

#define DEV static __device__ __forceinline__

DEV unsigned short f2bf(float f) {          // RNE float -> bf16 bits
  unsigned int u = __float_as_uint(f);
  u += 0x7FFFu + ((u >> 16) & 1u);
  return (unsigned short)(u >> 16);
}

DEV void gl_lds16(const unsigned short* g, unsigned short* l) {
  // async global->LDS, 16B per lane; LDS dest = wave-uniform base + lane*16
  __builtin_amdgcn_global_load_lds((const uint_g*)g, (uint_l*)l, 16, 0, 0);
}

// ---------- merged elementwise f32 -> bf16 for text+image (1 launch) ------
__global__ __launch_bounds__(256) void k_convert2(const float* __restrict__ a,
                                                  unsigned short* __restrict__ oa,
                                                  const float* __restrict__ b,
                                                  unsigned short* __restrict__ ob) {
  // a: 6144 blocks (1572864 float4), b: 9216 blocks (2359296 float4); exact fit
  const int id = blockIdx.x;
  const float* in;  unsigned short* out;  int i;
  if (id < 6144) { in = a; out = oa; i = id * 256 + threadIdx.x; }
  else           { in = b; out = ob; i = (id - 6144) * 256 + threadIdx.x; }
  const float4 v = ((const float4*)in)[i];
  ushort4 o;
  o.x = f2bf(v.x); o.y = f2bf(v.y); o.z = f2bf(v.z); o.w = f2bf(v.w);
  ((ushort4*)out)[i] = o;
}

// ---------- merged transpose fp32 [R][C] -> bf16 [C][R], all 6 weights ----
__global__ __launch_bounds__(256) void k_transpose_all(
    const float* __restrict__ wq, const float* __restrict__ wk,
    const float* __restrict__ wv, const float* __restrict__ wr,
    const float* __restrict__ w1, const float* __restrict__ w2,
    unsigned short* wqT, unsigned short* wkT, unsigned short* wvT,
    unsigned short* wrT, unsigned short* w1T, unsigned short* w2T) {
  __shared__ unsigned short tile[32][33];   // +1 pad breaks bank conflicts
  int id = blockIdx.x;
  const float* in; unsigned short* out; int R, C, bx, by;
  if (id < 1536)      {            in = wq; out = wqT; R = 768;  C = 2048; bx = id & 63; by = id >> 6; }
  else if (id < 3584) { id -= 1536; in = wk; out = wkT; R = 1024; C = 2048; bx = id & 63; by = id >> 6; }
  else if (id < 5632) { id -= 3584; in = wv; out = wvT; R = 1024; C = 2048; bx = id & 63; by = id >> 6; }
  else if (id < 7168) { id -= 5632; in = wr; out = wrT; R = 2048; C = 768;  bx = id % 24; by = id / 24; }
  else if (id < 7264) { id -= 7168; in = w1; out = w1T; R = 768;  C = 128;  bx = id & 3;  by = id >> 2; }
  else                { id -= 7264; in = w2; out = w2T; R = 128;  C = 768;  bx = id % 24; by = id / 24; }
  const int c0 = bx << 5, r0 = by << 5;
  const int tx = threadIdx.x & 31, ty = threadIdx.x >> 5;   // 32x8
  #pragma unroll
  for (int i = 0; i < 32; i += 8)
    tile[ty + i][tx] = f2bf(in[(size_t)(r0 + ty + i) * C + c0 + tx]);
  __syncthreads();
  #pragma unroll
  for (int i = 0; i < 32; i += 8)
    out[(size_t)(c0 + ty + i) * R + r0 + tx] = tile[tx][ty + i];
}

enum { EPI_BIAS = 0, EPI_VT = 3, EPI_DUAL = 4, EPI_RELU = 5, EPI_KV = 7 };

// ---------- 8-phase 256x256 bf16 GEMM body (r5 schedule, best measured) ----
// All ds_reads issue PRE-barrier (fresh-tile p0 reads legal: tile certified
// at the PREVIOUS tile's p3 vmcnt). One half-tile staged per phase:
//   p0 -> (kt+1)A1, p1 -> (kt+2)B0, p2 -> (kt+2)B1, p3 -> (kt+2)A0
// vmcnt(6) at p3 (after issue) certifies all of tile kt+1. Tail: vmcnt(0)
// at kTiles-2's p3. 2 raw s_barriers/phase, never vmcnt(0) in steady state.
// T2 swizzle: LDS[row][c16] = G[row][c16 ^ (row&7)], gl_lds dest linear.
template <int EPI>
DEV void gemm8_body(unsigned short (&As)[2][16384], unsigned short (&Bs)[2][16384],
                    const unsigned short* __restrict__ A, const unsigned short* __restrict__ B,
                    int lda, int ldb, int kTiles,
                    void* C0, void* C1, const float* bias, const float* bias2,
                    int ldc, float scale, int bx, int by) {
  const int t = threadIdx.x;
  const int lane = t & 63, w = t >> 6;
  const int wm = w >> 2, wn = w & 3;           // 2M x 4N wave grid
  const int frow = lane & 15, quad = lane >> 4;

  const unsigned short* Ab = A + (size_t)by * 256 * lda;
  const unsigned short* Bb = B + (size_t)bx * 256 * ldb;

  f32x4 acc[8][4] = {};

  auto stA = [&](int kt, int bi, int h) {
    #pragma unroll
    for (int it = 0; it < 2; ++it) {
      int e = (it << 9) + t;
      int row = (h << 7) + (e >> 3);
      int c16 = (e & 7) ^ (row & 7);
      gl_lds16(Ab + (size_t)row * lda + (kt << 6) + (c16 << 3),
               &As[bi][(row << 6) + ((e & 7) << 3)]);
    }
  };
  auto stB = [&](int kt, int bi, int h) {
    #pragma unroll
    for (int it = 0; it < 2; ++it) {
      int e = (it << 9) + t;
      int row = (h << 7) + (e >> 3);
      int c16 = (e & 7) ^ (row & 7);
      gl_lds16(Bb + (size_t)row * ldb + (kt << 6) + (c16 << 3),
               &Bs[bi][(row << 6) + ((e & 7) << 3)]);
    }
  };
  auto frag = [&](const unsigned short* buf, int row, int ksl) -> bf16x8 {
    int col = ((ksl << 5) + (quad << 3)) ^ ((row & 7) << 3);
    return *(const bf16x8*)&buf[(row << 6) + col];
  };

  // prologue -- FIFO: 0:B0,0:B1,0:A0,0:A1, 1:B0,1:B1,1:A0 (14 loads);
  // vmcnt(6) certifies tile0 (8 oldest), leaves {1:B0,B1,A0} = invariant.
  stB(0, 0, 0); stB(0, 0, 1); stA(0, 0, 0); stA(0, 0, 1);
  if (kTiles > 1) {
    stB(1, 1, 0); stB(1, 1, 1); stA(1, 1, 0);
    asm volatile("s_waitcnt vmcnt(6)" ::: "memory");
  } else {
    asm volatile("s_waitcnt vmcnt(0)" ::: "memory");
  }
  asm volatile("s_barrier" ::: "memory");      // cross-wave: tile0 visible

  bf16x8 a[4][2], b0[2][2], b1[2][2];
  const int arow = wm << 7, brow = wn << 6;

  for (int kt = 0; kt < kTiles; ++kt) {
    const int pb = kt & 1, qb = pb ^ 1;
    const unsigned short* Ac = As[pb];
    const unsigned short* Bc = Bs[pb];

    // ---- phase 0 : (mh0, nh0); reads PRE-barrier; stage (kt+1)A1 -> qb
    #pragma unroll
    for (int m = 0; m < 4; ++m)
      #pragma unroll
      for (int k = 0; k < 2; ++k) a[m][k] = frag(Ac, arow + (m << 4) + frow, k);
    #pragma unroll
    for (int n = 0; n < 2; ++n)
      #pragma unroll
      for (int k = 0; k < 2; ++k) b0[n][k] = frag(Bc, brow + (n << 4) + frow, k);
    if (kt + 1 < kTiles) stA(kt + 1, qb, 1);
    asm volatile("s_barrier" ::: "memory");
    asm volatile("s_waitcnt lgkmcnt(0)" ::: "memory");
    __builtin_amdgcn_s_setprio(1);
    #pragma unroll
    for (int m = 0; m < 4; ++m)
      #pragma unroll
      for (int n = 0; n < 2; ++n)
        #pragma unroll
        for (int k = 0; k < 2; ++k)
          acc[m][n] = __builtin_amdgcn_mfma_f32_16x16x32_bf16(a[m][k], b0[n][k], acc[m][n], 0, 0, 0);
    __builtin_amdgcn_s_setprio(0);
    asm volatile("s_barrier" ::: "memory");

    // ---- phase 1 : (mh0, nh1); stage (kt+2)B0 -> pb (B0 last read @p0)
    #pragma unroll
    for (int n = 0; n < 2; ++n)
      #pragma unroll
      for (int k = 0; k < 2; ++k) b1[n][k] = frag(Bc, brow + 32 + (n << 4) + frow, k);
    if (kt + 2 < kTiles) stB(kt + 2, pb, 0);
    asm volatile("s_barrier" ::: "memory");
    asm volatile("s_waitcnt lgkmcnt(0)" ::: "memory");
    __builtin_amdgcn_s_setprio(1);
    #pragma unroll
    for (int m = 0; m < 4; ++m)
      #pragma unroll
      for (int n = 0; n < 2; ++n)
        #pragma unroll
        for (int k = 0; k < 2; ++k)
          acc[m][2 + n] = __builtin_amdgcn_mfma_f32_16x16x32_bf16(a[m][k], b1[n][k], acc[m][2 + n], 0, 0, 0);
    __builtin_amdgcn_s_setprio(0);
    asm volatile("s_barrier" ::: "memory");

    // ---- phase 2 : (mh1, nh0); refill A regs; stage (kt+2)B1 (read @p1)
    #pragma unroll
    for (int m = 0; m < 4; ++m)
      #pragma unroll
      for (int k = 0; k < 2; ++k) a[m][k] = frag(Ac, arow + 64 + (m << 4) + frow, k);
    if (kt + 2 < kTiles) stB(kt + 2, pb, 1);
    asm volatile("s_barrier" ::: "memory");
    asm volatile("s_waitcnt lgkmcnt(0)" ::: "memory");
    __builtin_amdgcn_s_setprio(1);
    #pragma unroll
    for (int m = 0; m < 4; ++m)
      #pragma unroll
      for (int n = 0; n < 2; ++n)
        #pragma unroll
        for (int k = 0; k < 2; ++k)
          acc[4 + m][n] = __builtin_amdgcn_mfma_f32_16x16x32_bf16(a[m][k], b0[n][k], acc[4 + m][n], 0, 0, 0);
    __builtin_amdgcn_s_setprio(0);
    asm volatile("s_barrier" ::: "memory");

    // ---- phase 3 : (mh1, nh1); stage (kt+2)A0 (read @p0); certify kt+1
    if (kt + 2 < kTiles) {
      stA(kt + 2, pb, 0);
      asm volatile("s_waitcnt vmcnt(6)" ::: "memory");   // tile kt+1 resident
    } else if (kt + 1 < kTiles) {
      asm volatile("s_waitcnt vmcnt(0)" ::: "memory");   // last tile resident
    }
    asm volatile("s_barrier" ::: "memory");
    __builtin_amdgcn_s_setprio(1);
    #pragma unroll
    for (int m = 0; m < 4; ++m)
      #pragma unroll
      for (int n = 0; n < 2; ++n)
        #pragma unroll
        for (int k = 0; k < 2; ++k)
          acc[4 + m][2 + n] = __builtin_amdgcn_mfma_f32_16x16x32_bf16(a[m][k], b1[n][k], acc[4 + m][2 + n], 0, 0, 0);
    __builtin_amdgcn_s_setprio(0);
    asm volatile("s_barrier" ::: "memory");
  }

  // ---- epilogue: C/D layout col=lane&15, row=(lane>>4)*4+reg ----
  const int mb = by * 256 + wm * 128 + (quad << 2);
  const int nb = bx * 256 + wn * 64 + frow;
  #pragma unroll
  for (int mi = 0; mi < 8; ++mi) {
    const int m = mb + mi * 16;
    #pragma unroll
    for (int ni = 0; ni < 4; ++ni) {
      const int n = nb + ni * 16;
      f32x4 v = acc[mi][ni];
      if constexpr (EPI == EPI_BIAS) {
        unsigned short* O = (unsigned short*)C0;
        const float bv2 = bias[n];
        #pragma unroll
        for (int r = 0; r < 4; ++r) O[(size_t)(m + r) * ldc + n] = f2bf((v[r] + bv2) * scale);
      } else if constexpr (EPI == EPI_KV) {
        if (n < 2048) {                                  // K path (uniform per block)
          unsigned short* O = (unsigned short*)C0;
          const float bv2 = bias[n];
          #pragma unroll
          for (int r = 0; r < 4; ++r) O[(size_t)(m + r) * ldc + n] = f2bf(v[r] + bv2);
        } else {                                         // V path -> Vt[b][h][d][li]
          const int n2 = n - 2048;
          const int b = m / 576, li = m - b * 576;
          const int h = n2 >> 8, d = n2 & 255;
          const float bv2 = bias2[n2];
          ushort4 o;
          o.x = f2bf(v[0] + bv2); o.y = f2bf(v[1] + bv2);
          o.z = f2bf(v[2] + bv2); o.w = f2bf(v[3] + bv2);
          *(ushort4*)((unsigned short*)C1 + ((size_t)((b * 8 + h) * 256 + d)) * 576 + li) = o;
        }
      }
    }
  }
}

// ---------- fused Q + K|V projection: one dispatch pool, 832 blocks -------
// ids 0..575  : KV GEMM  image @ [wk|wv]^T  (16 cols x 36 rows, 16 K-tiles)
// ids 576..831: Q  GEMM  text  @ wq^T       (8 cols x 32 rows, 12 K-tiles)
// Long blocks first: dispatcher backfills KV's partial last round with Q.
__global__ __launch_bounds__(512, 2)
void k_qkv(const unsigned short* __restrict__ Tbf, const unsigned short* __restrict__ wqT,
           unsigned short* Qb, const float* bq, float qscale,
           const unsigned short* __restrict__ Ibf, const unsigned short* __restrict__ wkT,
           unsigned short* Kb, unsigned short* Vt, const float* bk, const float* bv) {
  __shared__ unsigned short As[2][16384];   // 64 KB
  __shared__ unsigned short Bs[2][16384];   // 64 KB
  const int id = blockIdx.x;
  if (id < 576) {
    gemm8_body<EPI_KV>(As, Bs, Ibf, wkT, 1024, 1024, 16,
                       Kb, Vt, bk, bv, 2048, 1.0f, id & 15, id >> 4);
  } else {
    const int q = id - 576;
    gemm8_body<EPI_BIAS>(As, Bs, Tbf, wqT, 768, 768, 12,
                         Qb, nullptr, bq, nullptr, 2048, qscale, q & 7, q >> 3);
  }
}

// ---------- generic bf16 MFMA GEMM: C = A @ B^T (+epilogue) ----------
// round-0 form (best 2-phase measured): single-barrier double-buffered K-loop.
// Used for out-proj / ff1 (shapes that don't fit 256x256 tiling).
template <int BM, int BN, int EPI>
__global__ __launch_bounds__(256)
void k_gemm(const unsigned short* __restrict__ A, const unsigned short* __restrict__ B,
            int lda, int ldb, int kSteps,
            void* C0, void* C1, const float* bias, const float* resid, int ldc, float scale) {
  constexpr int TM = BM / 32;
  constexpr int TN = BN / 32;
  __shared__ unsigned short At[2][BM * 32];
  __shared__ unsigned short Bt[2][BN * 32];

  const int t = threadIdx.x;
  const int lane = t & 63, wave = t >> 6;
  const int wm = wave >> 1, wn = wave & 1;            // 2x2 wave grid

  const unsigned short* Ab = A + (size_t)blockIdx.y * BM * lda;
  const unsigned short* Bb = B + (size_t)blockIdx.x * BN * ldb;

  const int frow = lane & 15, fk = (lane >> 4) << 3;

  f32x4 acc[TM][TN] = {};

  auto stage = [&](int ks, int bi) {
    const int k0 = ks << 5;
    #pragma unroll
    for (int r = 0; r < BM / 64; ++r) {
      int off16 = (r << 8) + t;
      int row = off16 >> 2, kk = (off16 & 3) << 3;
      gl_lds16(Ab + (size_t)row * lda + k0 + kk, &At[bi][(row << 5) + kk]);
    }
    #pragma unroll
    for (int r = 0; r < BN / 64; ++r) {
      int off16 = (r << 8) + t;
      int row = off16 >> 2, kk = (off16 & 3) << 3;
      gl_lds16(Bb + (size_t)row * ldb + k0 + kk, &Bt[bi][(row << 5) + kk]);
    }
  };

  stage(0, 0);

  for (int ks = 0; ks < kSteps; ++ks) {
    const int buf = ks & 1;
    __syncthreads();                        // drains prefetch for buf; prev reads done
    if (ks + 1 < kSteps) stage(ks + 1, buf ^ 1);

    bf16x8 af[TM], bv[TN];
    #pragma unroll
    for (int mi = 0; mi < TM; ++mi)
      af[mi] = *(const bf16x8*)&At[buf][((wm * (BM / 2) + mi * 16 + frow) << 5) + fk];
    #pragma unroll
    for (int ni = 0; ni < TN; ++ni)
      bv[ni] = *(const bf16x8*)&Bt[buf][((wn * (BN / 2) + ni * 16 + frow) << 5) + fk];
    #pragma unroll
    for (int mi = 0; mi < TM; ++mi)
      #pragma unroll
      for (int ni = 0; ni < TN; ++ni)
        acc[mi][ni] = __builtin_amdgcn_mfma_f32_16x16x32_bf16(af[mi], bv[ni], acc[mi][ni], 0, 0, 0);
  }

  // C/D layout (m89-verified): col = lane&15, row = (lane>>4)*4 + reg
  const int mb = blockIdx.y * BM + wm * (BM / 2) + ((lane >> 4) << 2);
  const int nb = blockIdx.x * BN + wn * (BN / 2) + (lane & 15);

  #pragma unroll
  for (int mi = 0; mi < TM; ++mi) {
    const int m = mb + mi * 16;
    #pragma unroll
    for (int ni = 0; ni < TN; ++ni) {
      const int n = nb + ni * 16;
      f32x4 v = acc[mi][ni];
      if constexpr (EPI == EPI_BIAS) {                 // bf16((acc + bias[n]) * scale)
        unsigned short* O = (unsigned short*)C0;
        const float bv2 = bias[n];
        #pragma unroll
        for (int r = 0; r < 4; ++r) O[(size_t)(m + r) * ldc + n] = f2bf((v[r] + bv2) * scale);
      } else if constexpr (EPI == EPI_DUAL) {          // out-proj: fp32 + bf16 copies
        float* Of = (float*)C0;
        unsigned short* Ob = (unsigned short*)C1;
        const float bv2 = bias[n];
        #pragma unroll
        for (int r = 0; r < 4; ++r) {
          const float x = v[r] + bv2;
          const size_t idx = (size_t)(m + r) * ldc + n;
          Of[idx] = x; Ob[idx] = f2bf(x);
        }
      } else if constexpr (EPI == EPI_RELU) {          // ff1: bf16(relu(acc+bias))
        unsigned short* O = (unsigned short*)C0;
        const float bv2 = bias[n];
        #pragma unroll
        for (int r = 0; r < 4; ++r) {
          const float x = v[r] + bv2;
          O[(size_t)(m + r) * ldc + n] = f2bf(x > 0.f ? x : 0.f);
        }
      }
    }
  }
}

// ---------- fused flash attention v4 ----------
// Q [8192][2048] bf16 (pre-scaled by log2(e)/16 => P = exp2(S), fixed-max
// softmax, no rescale). K [9216][2048] bf16, Vt [bh=128][d=256][li=576] bf16,
// X [8192][2048] bf16.
__global__ __launch_bounds__(512, 2)
void k_flash(const unsigned short* __restrict__ Q, const unsigned short* __restrict__ K,
             const unsigned short* __restrict__ Vt, unsigned short* __restrict__ X) {
  __shared__ unsigned short Ks[2][8 * 32 * 32];  // 16 KB x2  [kd8][li32][32]
  __shared__ unsigned short Vs[2][256 * 32];     // 16 KB x2  [d256][32li]
  __shared__ unsigned short Ps[256 * 40];        // 20 KB     [q256][li32] stride 40
  __shared__ unsigned short Ones[512];           //  1 KB     ones-column B-tile

  const int t = threadIdx.x, lane = t & 63, w = t >> 6;
  const int frow = lane & 15, quad = lane >> 4, fk = quad << 3;

  // XCD swizzle: id&7 = XCD; both q-blocks of one bh land on the same XCD
  const int id = blockIdx.x;
  const int qb = (id >> 3) & 1;
  const int bh = (id & 7) | ((id >> 4) << 3);
  const int b = bh >> 3, h = bh & 7;
  const int q0 = qb << 8;

  const unsigned short* Kg = K + ((size_t)b * 576) * 2048 + h * 256;
  const unsigned short* Vg = Vt + (size_t)bh * 147456;

  Ones[t] = (t < 32) ? (unsigned short)0x3F80 : (unsigned short)0;

  // Q fragments resident in VGPRs: wave w owns q rows q0+32w .. +31
  bf16x8 Qf[2][8];
  #pragma unroll
  for (int half = 0; half < 2; ++half) {
    const unsigned short* Qg =
        Q + ((size_t)(b * 512 + q0 + w * 32 + half * 16 + frow)) * 2048 + h * 256;
    #pragma unroll
    for (int kd = 0; kd < 8; ++kd)
      Qf[half][kd] = *(const bf16x8*)(Qg + kd * 32 + fk);
  }

  f32x4 acc_o[2][17] = {};   // [half][16 d-tiles + l]

  auto stage = [&](int s, int bi) {
    const int li0 = s << 5;
    unsigned short* Kb = &Ks[bi][0];
    unsigned short* Vb = &Vs[bi][0];
    #pragma unroll
    for (int it = 0; it < 2; ++it) {
      int e = (it << 9) + t;                    // 16B-chunk index, 0..1023
      int row = e >> 2, c = (e & 3) << 3;       // row = kd*32+li
      int kd = row >> 5, li = row & 31;
      gl_lds16(Kg + (size_t)(li0 + li) * 2048 + kd * 32 + c, &Kb[(row << 5) + c]);
    }
    #pragma unroll
    for (int it = 0; it < 2; ++it) {
      int e = (it << 9) + t;
      int d = e >> 2, c = (e & 3) << 3;
      gl_lds16(Vg + (size_t)d * 576 + li0 + c, &Vb[(d << 5) + c]);
    }
  };

  stage(0, 0);

  const int prow = (w << 5) + (quad << 2);     // Ps write row base (q within 256)

  for (int s = 0; s < 18; ++s) {
    const int buf = s & 1;
    __syncthreads();                 // drains vmcnt: buf(s) ready; prev consumed
    if (s + 1 < 18) stage(s + 1, buf ^ 1);

    // ---- S = Q_w @ K^T : 32 q x 32 li (K reads shared across halves) ----
    f32x4 acc_s[2][2] = {};
    #pragma unroll
    for (int kd = 0; kd < 8; ++kd) {
      #pragma unroll
      for (int ni = 0; ni < 2; ++ni) {
        const bf16x8 bv = *(const bf16x8*)&Ks[buf][((kd * 32 + ni * 16 + frow) << 5) + fk];
        acc_s[0][ni] = __builtin_amdgcn_mfma_f32_16x16x32_bf16(Qf[0][kd], bv, acc_s[0][ni], 0, 0, 0);
        acc_s[1][ni] = __builtin_amdgcn_mfma_f32_16x16x32_bf16(Qf[1][kd], bv, acc_s[1][ni], 0, 0, 0);
      }
    }

    // ---- P = exp2(S) (log2e folded into Q scale), write own Ps rows ----
    #pragma unroll
    for (int half = 0; half < 2; ++half)
      #pragma unroll
      for (int ni = 0; ni < 2; ++ni)
        #pragma unroll
        for (int r = 0; r < 4; ++r)
          Ps[(prow + half * 16 + r) * 40 + ni * 16 + frow] =
              f2bf(__builtin_amdgcn_exp2f(acc_s[half][ni][r]));

    // ---- O += P_w @ [V | 1]^T : 32q x 272d (V reads shared across halves) ----
    bf16x8 paf[2];
    paf[0] = *(const bf16x8*)&Ps[((w << 5) + frow) * 40 + fk];
    paf[1] = *(const bf16x8*)&Ps[((w << 5) + 16 + frow) * 40 + fk];
    #pragma unroll
    for (int ni = 0; ni < 16; ++ni) {
      const bf16x8 bv = *(const bf16x8*)&Vs[buf][((ni * 16 + frow) << 5) + fk];
      acc_o[0][ni] = __builtin_amdgcn_mfma_f32_16x16x32_bf16(paf[0], bv, acc_o[0][ni], 0, 0, 0);
      acc_o[1][ni] = __builtin_amdgcn_mfma_f32_16x16x32_bf16(paf[1], bv, acc_o[1][ni], 0, 0, 0);
    }
    {
      const bf16x8 bv = *(const bf16x8*)&Ones[(frow << 5) + fk];
      acc_o[0][16] = __builtin_amdgcn_mfma_f32_16x16x32_bf16(paf[0], bv, acc_o[0][16], 0, 0, 0);
      acc_o[1][16] = __builtin_amdgcn_mfma_f32_16x16x32_bf16(paf[1], bv, acc_o[1][16], 0, 0, 0);
    }
  }

  // ---- epilogue: l in acc_o[half][16] on lanes frow==0; broadcast in-quad ----
  #pragma unroll
  for (int half = 0; half < 2; ++half) {
    float linv[4];
    #pragma unroll
    for (int r = 0; r < 4; ++r)
      linv[r] = 1.0f / __shfl(acc_o[half][16][r], lane & 48);
    unsigned short* Xo = X + ((size_t)(b * 512 + q0 + w * 32 + half * 16 + (quad << 2))) * 2048 +
                         h * 256 + frow;
    #pragma unroll
    for (int ni = 0; ni < 16; ++ni)
      #pragma unroll
      for (int r = 0; r < 4; ++r)
        Xo[(size_t)r * 2048 + ni * 16] = f2bf(acc_o[half][ni][r] * linv[r]);
  }
}

// ---------- fused ff2 + LayerNorm ----------
// Per block: 32 full rows (768 cols). h @ w2 with K=128 read straight from
// global (Hb 2MB + w2T 192KB are L2-resident), + bias + fp32 residual from
// Out, then LN over the full row in-block: in-register quad reduce (shfl_xor
// over frow) + tiny LDS cross-wave combine. Saves LN's 50MB pass + 1 launch.
// 256 thr = 4 waves; wave w owns cols [w*192, w*192+192) as 12 16-col tiles.
__global__ __launch_bounds__(256)
void k_ff2_ln(const unsigned short* __restrict__ Hb, const unsigned short* __restrict__ w2T,
              const float* __restrict__ b2, float* __restrict__ Out,
              const float* __restrict__ gamma, const float* __restrict__ beta) {
  const int t = threadIdx.x, lane = t & 63, w = t >> 6;
  const int frow = lane & 15, quad = lane >> 4, fk = quad << 3;
  const int m0 = blockIdx.x << 5;                 // 32 rows per block

  f32x4 acc[2][12] = {};
  #pragma unroll
  for (int ks = 0; ks < 4; ++ks) {
    bf16x8 a[2];
    #pragma unroll
    for (int mi = 0; mi < 2; ++mi)
      a[mi] = *(const bf16x8*)(Hb + (size_t)(m0 + mi * 16 + frow) * 128 + ks * 32 + fk);
    #pragma unroll
    for (int ni = 0; ni < 12; ++ni) {
      const bf16x8 b = *(const bf16x8*)(w2T + (size_t)(w * 192 + ni * 16 + frow) * 128 + ks * 32 + fk);
      acc[0][ni] = __builtin_amdgcn_mfma_f32_16x16x32_bf16(a[0], b, acc[0][ni], 0, 0, 0);
      acc[1][ni] = __builtin_amdgcn_mfma_f32_16x16x32_bf16(a[1], b, acc[1][ni], 0, 0, 0);
    }
  }

  // bias + residual (fp32 from Out); accumulate per-row partial sums.
  // C/D layout: col = frow, row (within 16-tile) = quad*4 + r.
  float s8[2][4] = {}, q8[2][4] = {};
  #pragma unroll
  for (int mi = 0; mi < 2; ++mi)
    #pragma unroll
    for (int ni = 0; ni < 12; ++ni) {
      const int n = w * 192 + ni * 16 + frow;
      const float bv = b2[n];
      #pragma unroll
      for (int r = 0; r < 4; ++r) {
        const int row = m0 + mi * 16 + (quad << 2) + r;
        const float x = acc[mi][ni][r] + bv + Out[(size_t)row * 768 + n];
        acc[mi][ni][r] = x;
        s8[mi][r] += x; q8[mi][r] += x * x;
      }
    }
  // reduce across the 16 frow lanes of each quad (masks 1..8 stay in-quad)
  #pragma unroll
  for (int msk = 1; msk <= 8; msk <<= 1)
    #pragma unroll
    for (int mi = 0; mi < 2; ++mi)
      #pragma unroll
      for (int r = 0; r < 4; ++r) {
        s8[mi][r] += __shfl_xor(s8[mi][r], msk);
        q8[mi][r] += __shfl_xor(q8[mi][r], msk);
      }
  __shared__ float redS[4][32], redQ[4][32];
  if (frow == 0) {
    #pragma unroll
    for (int mi = 0; mi < 2; ++mi)
      #pragma unroll
      for (int r = 0; r < 4; ++r) {
        const int r32 = mi * 16 + (quad << 2) + r;
        redS[w][r32] = s8[mi][r]; redQ[w][r32] = q8[mi][r];
      }
  }
  __syncthreads();
  #pragma unroll
  for (int mi = 0; mi < 2; ++mi)
    #pragma unroll
    for (int r = 0; r < 4; ++r) {
      const int r32 = mi * 16 + (quad << 2) + r;
      const float S = redS[0][r32] + redS[1][r32] + redS[2][r32] + redS[3][r32];
      const float Qq = redQ[0][r32] + redQ[1][r32] + redQ[2][r32] + redQ[3][r32];
      const float mu = S * (1.0f / 768.0f);
      const float var = Qq * (1.0f / 768.0f) - mu * mu;
      const float inv = rsqrtf(var + 1e-5f);
      const size_t rowoff = (size_t)(m0 + r32) * 768;
      #pragma unroll
      for (int ni = 0; ni < 12; ++ni) {
        const int n = w * 192 + ni * 16 + frow;
        Out[rowoff + n] = (acc[mi][ni][r] - mu) * inv * gamma[n] + beta[n];
      }
    }
}

// ---------- host ----------
extern "C" void kernel_launch(void* const* d_in, const int* in_sizes, int n_in,
                              void* d_out, int out_size, void* d_ws, size_t ws_size,
                              hipStream_t stream) {
  const float* text  = (const float*)d_in[0];
  const float* image = (const float*)d_in[1];
  const float* wq = (const float*)d_in[2];  const float* bq = (const float*)d_in[3];
  const float* wk = (const float*)d_in[4];  const float* bk = (const float*)d_in[5];
  const float* wv = (const float*)d_in[6];  const float* bv = (const float*)d_in[7];
  const float* wr = (const float*)d_in[8];  const float* br = (const float*)d_in[9];
  const float* w1 = (const float*)d_in[10]; const float* b1 = (const float*)d_in[11];
  const float* w2 = (const float*)d_in[12]; const float* b2 = (const float*)d_in[13];
  const float* gamma = (const float*)d_in[14]; const float* beta = (const float*)d_in[15];

  uint8_t* ws = (uint8_t*)d_ws;
  constexpr size_t o_Tbf = 0;
  constexpr size_t o_Ibf = 12582912;                 // 8192*768*2
  constexpr size_t o_X   = 0;                        // reuse region0 (disjoint lifetime)
  constexpr size_t o_Q   = 33554432;
  constexpr size_t o_Kb  = o_Q   + 33554432;         // 8192*2048*2
  constexpr size_t o_Vt  = o_Kb  + 37748736;         // 9216*2048*2
  constexpr size_t o_wqT = o_Vt  + 37748736;
  constexpr size_t o_wkT = o_wqT + 3145728;          // wkT: rows 0..2047 of fused B
  constexpr size_t o_wvT = o_wkT + 4194304;          // wvT: rows 2048..4095 (contiguous!)
  constexpr size_t o_wrT = o_wvT + 4194304;
  constexpr size_t o_w1T = o_wrT + 3145728;
  constexpr size_t o_w2T = o_w1T + 196608;
  constexpr size_t o_OutB= o_w2T + 196608;
  constexpr size_t o_H   = o_OutB+ 12582912;         // 8192*768*2

  unsigned short* Tbf  = (unsigned short*)(ws + o_Tbf);
  unsigned short* Ibf  = (unsigned short*)(ws + o_Ibf);
  unsigned short* Xb   = (unsigned short*)(ws + o_X);
  unsigned short* Qb   = (unsigned short*)(ws + o_Q);
  unsigned short* Kb   = (unsigned short*)(ws + o_Kb);
  unsigned short* Vt   = (unsigned short*)(ws + o_Vt);
  unsigned short* wqT  = (unsigned short*)(ws + o_wqT);
  unsigned short* wkT  = (unsigned short*)(ws + o_wkT);
  unsigned short* wvT  = (unsigned short*)(ws + o_wvT);
  unsigned short* wrT  = (unsigned short*)(ws + o_wrT);
  unsigned short* w1T  = (unsigned short*)(ws + o_w1T);
  unsigned short* w2T  = (unsigned short*)(ws + o_w2T);
  unsigned short* OutB = (unsigned short*)(ws + o_OutB);
  unsigned short* Hb   = (unsigned short*)(ws + o_H);
  float* OutF = (float*)d_out;

  const dim3 blk(256);

  // --- prep: 2 launches (was 8) ---
  k_convert2<<<dim3(15360), blk, 0, stream>>>(text, Tbf, image, Ibf);
  k_transpose_all<<<dim3(7360), blk, 0, stream>>>(wq, wk, wv, wr, w1, w2,
                                                  wqT, wkT, wvT, wrT, w1T, w2T);

  // --- fused Q + K|V projections: one 832-block pool (KV first, Q backfills)
  k_qkv<<<dim3(832), dim3(512), 0, stream>>>(
      Tbf, wqT, Qb, bq, 0.0625f * 1.44269504f,
      Ibf, wkT, Kb, Vt, bk, bv);

  // --- fused attention: X = softmax(QK^T)V ---
  k_flash<<<dim3(256), dim3(512), 0, stream>>>(Qb, Kb, Vt, Xb);

  // --- out = X @ wr + br : fp32 into d_out + bf16 copy for FF ---
  k_gemm<128, 128, EPI_DUAL><<<dim3(6, 64), blk, 0, stream>>>(
      Xb, wrT, 2048, 2048, 64, OutF, OutB, br, nullptr, 768, 1.0f);

  // --- h = relu(out @ w1 + b1) : [8192,128], 64x64 tiles for 256 blocks ---
  k_gemm<64, 64, EPI_RELU><<<dim3(2, 128), blk, 0, stream>>>(
      OutB, w1T, 768, 768, 24, Hb, nullptr, b1, nullptr, 128, 1.0f);

  // --- out = LN(out + h @ w2 + b2) : fused ff2 + LayerNorm, 256 blocks ---
  k_ff2_ln<<<dim3(256), blk, 0, stream>>>(Hb, w2T, b2, OutF, gamma, beta);

  (void)in_sizes; (void)n_in; (void)out_size; (void)ws_size;
}